// Round 4
// baseline (352.990 us; speedup 1.0000x reference)
//
#include <hip/hip_runtime.h>
#include <cstdint>

// GIN: N=50000, D=128, E=800000, L=3.
// per layer: agg = x + gather-sum over CSR(dst); h = relu(agg@W1+b1); x = relu(h@W2+b2)
// CSR built once per launch. All feature math in f16 (fp32 accumulate), MFMA GEMMs.
// CSR bucket-scatter is dst-range-partitioned (8 ranges, aligned to XCDs via
// blockIdx&7) so ssrc writes stay in one XCD's L2 window -> 1 writeback/line.

constexpr int N = 50000;
constexpr int D = 128;
constexpr int E = 800000;
constexpr int L = 3;
constexpr int NB_SCAN = (N + 255) / 256;  // 196
constexpr int PART = 8;
constexpr int NPN = N / PART;             // 6250 nodes per partition
constexpr int BLK_PER_PART = 128;

typedef _Float16 f16;
typedef _Float16 f16x8 __attribute__((ext_vector_type(8)));
typedef float f32x4 __attribute__((ext_vector_type(4)));

// ---- edge index load (handles int32 or int64 storage) ----
__device__ __forceinline__ bool ei_is64(const int* ei) {
  return (ei[1] == 0) && (ei[3] == 0) && (ei[5] == 0);
}
__device__ __forceinline__ int ei_src(const int* ei, int e, bool is64) {
  return is64 ? ei[2 * (size_t)e] : ei[e];
}
__device__ __forceinline__ int ei_dst(const int* ei, int e, bool is64) {
  return is64 ? ei[2 * ((size_t)E + e)] : ei[(size_t)E + e];
}

// ---------------- CSR build ----------------
// prep: convert edge index to int32 arrays + histogram of dst
__global__ __launch_bounds__(256) void k_prep(const int* __restrict__ ei,
                                              int* __restrict__ src32,
                                              int* __restrict__ dst32,
                                              int* __restrict__ cnt) {
  int e = blockIdx.x * 256 + threadIdx.x;
  if (e >= E) return;
  bool is64 = ei_is64(ei);
  int s = ei_src(ei, e, is64);
  int t = ei_dst(ei, e, is64);
  src32[e] = s;
  dst32[e] = t;
  atomicAdd(cnt + t, 1);
}

__global__ __launch_bounds__(256) void k_scan1(const int* __restrict__ cnt,
                                               int* __restrict__ off,
                                               int* __restrict__ bsum) {
  __shared__ int s[256];
  int i = blockIdx.x * 256 + threadIdx.x;
  int v = (i < N) ? cnt[i] : 0;
  s[threadIdx.x] = v;
  __syncthreads();
#pragma unroll
  for (int o = 1; o < 256; o <<= 1) {
    int t = (threadIdx.x >= o) ? s[threadIdx.x - o] : 0;
    __syncthreads();
    s[threadIdx.x] += t;
    __syncthreads();
  }
  if (i < N) off[i] = s[threadIdx.x] - v;
  if (threadIdx.x == 255) bsum[blockIdx.x] = s[255];
}

__global__ __launch_bounds__(256) void k_scan2(int* __restrict__ bsum) {
  __shared__ int s[256];
  int v = (threadIdx.x < NB_SCAN) ? bsum[threadIdx.x] : 0;
  s[threadIdx.x] = v;
  __syncthreads();
#pragma unroll
  for (int o = 1; o < 256; o <<= 1) {
    int t = (threadIdx.x >= o) ? s[threadIdx.x - o] : 0;
    __syncthreads();
    s[threadIdx.x] += t;
    __syncthreads();
  }
  if (threadIdx.x < NB_SCAN) bsum[threadIdx.x] = s[threadIdx.x] - v;
}

__global__ __launch_bounds__(256) void k_scan3(int* __restrict__ off,
                                               const int* __restrict__ bsum,
                                               int* __restrict__ pos) {
  int i = blockIdx.x * 256 + threadIdx.x;
  if (i < N) {
    int o = off[i] + bsum[i >> 8];
    off[i] = o;
    pos[i] = o;
  }
  if (i == 0) off[N] = E;
}

// bucket-scatter, dst-range partitioned. partition = blockIdx&7 -> one XCD
// (round-robin dispatch), so each partition's ssrc window (~400KB) stays in
// that XCD's L2 and each line is written back once.
__global__ __launch_bounds__(256) void k_bucket_part(const int* __restrict__ src32,
                                                     const int* __restrict__ dst32,
                                                     int* __restrict__ pos,
                                                     int* __restrict__ ssrc) {
  const int part = blockIdx.x & (PART - 1);
  const int bi = blockIdx.x >> 3;  // 0..BLK_PER_PART-1
  const int lo = part * NPN;
  for (int e = bi * 256 + threadIdx.x; e < E; e += BLK_PER_PART * 256) {
    int d = dst32[e];
    if ((unsigned)(d - lo) < (unsigned)NPN) {
      int p = atomicAdd(pos + d, 1);
      ssrc[p] = src32[e];
    }
  }
}

// ---------------- conversions ----------------
__global__ __launch_bounds__(256) void k_cvt(const float* __restrict__ in,
                                             f16* __restrict__ out) {
  int i = blockIdx.x * 256 + threadIdx.x;
  float4 v0 = *(const float4*)(in + (size_t)i * 8);
  float4 v1 = *(const float4*)(in + (size_t)i * 8 + 4);
  f16x8 o = {(f16)v0.x, (f16)v0.y, (f16)v0.z, (f16)v0.w,
             (f16)v1.x, (f16)v1.y, (f16)v1.z, (f16)v1.w};
  *(f16x8*)(out + (size_t)i * 8) = o;
}

// weights: Wt[m][c][k] = Wsrc[m][k][c] as f16, m in [0,2L): first L from W1, rest W2
__global__ __launch_bounds__(256) void k_wprep(const float* __restrict__ W1,
                                               const float* __restrict__ W2,
                                               f16* __restrict__ Wt) {
  int i = blockIdx.x * 256 + threadIdx.x;  // 2*L*D*D = 98304, grid exact
  int m = i >> 14;
  int c = (i >> 7) & 127;
  int k = i & 127;
  const float* src = (m < L) ? (W1 + (size_t)m * D * D)
                             : (W2 + (size_t)(m - L) * D * D);
  Wt[i] = (f16)src[(size_t)k * D + c];
}

// ---------------- gather-aggregate (f16): agg[n] = x[n] + sum_{j} x[src_j]
// 256 threads = 16 groups x 16 lanes; each group handles 4 nodes serially
// (smooths Poisson degree variance); lane owns 8 contiguous dims (16B).
__global__ __launch_bounds__(256) void k_gather_f16(const f16* __restrict__ x,
                                                    const int* __restrict__ off,
                                                    const int* __restrict__ ssrc,
                                                    f16* __restrict__ agg) {
  const int grp = threadIdx.x >> 4;
  const int d0 = (threadIdx.x & 15) << 3;
  const int n0 = blockIdx.x * 64 + grp * 4;
#pragma unroll
  for (int q = 0; q < 4; ++q) {
    int n = n0 + q;
    if (n >= N) return;
    f16x8 v = *(const f16x8*)(x + (size_t)n * D + d0);
    float acc[8];
#pragma unroll
    for (int j = 0; j < 8; ++j) acc[j] = (float)v[j];
    int beg = off[n], end = off[n + 1];
    for (int p = beg; p < end; ++p) {
      int s = ssrc[p];
      f16x8 u = *(const f16x8*)(x + (size_t)s * D + d0);
#pragma unroll
      for (int j = 0; j < 8; ++j) acc[j] += (float)u[j];
    }
    f16x8 o;
#pragma unroll
    for (int j = 0; j < 8; ++j) o[j] = (f16)acc[j];
    *(f16x8*)(agg + (size_t)n * D + d0) = o;
  }
}

// ---------------- MFMA GEMM + bias + ReLU ----------------
// C[N,128] = relu(A[N,128] @ W[128,128] + b), A f16 row-major, Wt f16 [col][k].
// Block: 256 thr = 4 waves, 64 rows (16 per wave). mfma_f32_16x16x32_f16.
__global__ __launch_bounds__(256) void k_gemm_f16(const f16* __restrict__ A,
                                                  const f16* __restrict__ Wt,
                                                  const float* __restrict__ bias,
                                                  f16* __restrict__ Ch,
                                                  float* __restrict__ Cf) {
  __shared__ f16 Ws[128 * 136];  // rows padded 128->136 (2-way bank alias = free)
  {
    const f16x8* gsrc = (const f16x8*)Wt;
    for (int i = threadIdx.x; i < 2048; i += 256) {
      int c = i >> 4;
      int k8 = (i & 15) << 3;
      *(f16x8*)&Ws[c * 136 + k8] = gsrc[i];
    }
  }
  __syncthreads();

  const int w = threadIdx.x >> 6;
  const int l = threadIdx.x & 63;
  const int l15 = l & 15;
  const int g = l >> 4;
  const int r0 = blockIdx.x * 64 + w * 16;

  const int arow = min(r0 + l15, N - 1);
  const f16* Arow = A + (size_t)arow * D;
  f16x8 a[4];
#pragma unroll
  for (int t = 0; t < 4; ++t)
    a[t] = *(const f16x8*)(Arow + t * 32 + g * 8);

  float bcol[8];
#pragma unroll
  for (int c = 0; c < 8; ++c) bcol[c] = bias[c * 16 + l15];

  f32x4 acc[8];
#pragma unroll
  for (int c = 0; c < 8; ++c) acc[c] = (f32x4){0.f, 0.f, 0.f, 0.f};

#pragma unroll
  for (int t = 0; t < 4; ++t) {
#pragma unroll
    for (int c = 0; c < 8; ++c) {
      f16x8 b = *(const f16x8*)&Ws[(c * 16 + l15) * 136 + t * 32 + g * 8];
      acc[c] = __builtin_amdgcn_mfma_f32_16x16x32_f16(a[t], b, acc[c], 0, 0, 0);
    }
  }

#pragma unroll
  for (int r = 0; r < 4; ++r) {
    int rr = r0 + g * 4 + r;
    if (rr < N) {
#pragma unroll
      for (int c = 0; c < 8; ++c) {
        int col = c * 16 + l15;
        float vv = fmaxf(acc[c][r] + bcol[c], 0.0f);
        Ch[(size_t)rr * D + col] = (f16)vv;
        if (Cf) Cf[(size_t)rr * D + col] = vv;
      }
    }
  }
}

extern "C" void kernel_launch(void* const* d_in, const int* in_sizes, int n_in,
                              void* d_out, int out_size, void* d_ws, size_t ws_size,
                              hipStream_t stream) {
  const float* x0 = (const float*)d_in[0];
  const int* ei   = (const int*)d_in[1];
  const float* W1 = (const float*)d_in[2];
  const float* b1 = (const float*)d_in[3];
  const float* W2 = (const float*)d_in[4];
  const float* b2 = (const float*)d_in[5];
  float* out = (float*)d_out;

  // workspace layout
  f16* xh    = (f16*)d_ws;                        // N*D
  f16* aggh  = xh + (size_t)N * D;                // N*D
  f16* hh    = aggh + (size_t)N * D;              // N*D
  f16* Wt    = hh + (size_t)N * D;                // 2*L*D*D
  int* off   = (int*)(Wt + (size_t)2 * L * D * D);  // N+1
  int* pos   = off + (N + 1);                     // N
  int* bsum  = pos + N;                           // 256
  int* ssrc  = bsum + 256;                        // E
  int* src32 = ssrc + E;                          // E
  int* dst32 = src32 + E;                         // E

  const dim3 blk(256);

  // ---- one-time prep ----
  k_wprep<<<(2 * L * D * D) / 256, blk, 0, stream>>>(W1, W2, Wt);
  k_cvt<<<(N * D / 8 + 255) / 256, blk, 0, stream>>>(x0, xh);

  hipMemsetAsync(pos, 0, (size_t)N * sizeof(int), stream);
  k_prep<<<(E + 255) / 256, blk, 0, stream>>>(ei, src32, dst32, pos);
  k_scan1<<<NB_SCAN, blk, 0, stream>>>(pos, off, bsum);
  k_scan2<<<1, blk, 0, stream>>>(bsum);
  k_scan3<<<NB_SCAN, blk, 0, stream>>>(off, bsum, pos);
  k_bucket_part<<<PART * BLK_PER_PART, blk, 0, stream>>>(src32, dst32, pos, ssrc);

  const int gemm_blocks = (N + 63) / 64;   // 782
  const int gather_blocks = (N + 63) / 64; // 782

  for (int l = 0; l < L; ++l) {
    k_gather_f16<<<gather_blocks, blk, 0, stream>>>(xh, off, ssrc, aggh);
    k_gemm_f16<<<gemm_blocks, blk, 0, stream>>>(aggh, Wt + (size_t)l * D * D,
                                                b1 + (size_t)l * D, hh, nullptr);
    k_gemm_f16<<<gemm_blocks, blk, 0, stream>>>(hh, Wt + (size_t)(L + l) * D * D,
                                                b2 + (size_t)l * D, xh,
                                                (l == L - 1) ? out : nullptr);
  }
}

// Round 5
// 245.428 us; speedup vs baseline: 1.4383x; 1.4383x over previous
//
#include <hip/hip_runtime.h>
#include <cstdint>

// GIN: N=50000, D=128, E=800000, L=3.
// per layer: agg = x + gather-sum over CSR(dst); x' = relu(relu(agg@W1+b1)@W2+b2)
// CSR built once per launch. Feature math in f16 (fp32 accum), MFMA GEMMs.
// - bucket-scatter dst-range-partitioned (8 ranges ~ XCDs) to avoid write thrash
// - gather: 16 lanes/node, 3125 blocks, 4-way unrolled neighbor loop (MLP)
// - both GEMMs of a layer fused in one kernel; h lives in LDS only

constexpr int N = 50000;
constexpr int D = 128;
constexpr int E = 800000;
constexpr int L = 3;
constexpr int NB_SCAN = (N + 255) / 256;  // 196
constexpr int PART = 8;
constexpr int NPN = N / PART;             // 6250
constexpr int BLK_PER_PART = 128;
constexpr int WROW = 136;                 // padded LDS row (f16) for W / h tiles

typedef _Float16 f16;
typedef _Float16 f16x8 __attribute__((ext_vector_type(8)));
typedef float f32x4 __attribute__((ext_vector_type(4)));

// ---- edge index load (handles int32 or int64 storage) ----
__device__ __forceinline__ bool ei_is64(const int* ei) {
  return (ei[1] == 0) && (ei[3] == 0) && (ei[5] == 0);
}
__device__ __forceinline__ int ei_src(const int* ei, int e, bool is64) {
  return is64 ? ei[2 * (size_t)e] : ei[e];
}
__device__ __forceinline__ int ei_dst(const int* ei, int e, bool is64) {
  return is64 ? ei[2 * ((size_t)E + e)] : ei[(size_t)E + e];
}

// ---------------- CSR build ----------------
__global__ __launch_bounds__(256) void k_prep(const int* __restrict__ ei,
                                              int* __restrict__ src32,
                                              int* __restrict__ dst32,
                                              int* __restrict__ cnt) {
  int e = blockIdx.x * 256 + threadIdx.x;
  if (e >= E) return;
  bool is64 = ei_is64(ei);
  int s = ei_src(ei, e, is64);
  int t = ei_dst(ei, e, is64);
  src32[e] = s;
  dst32[e] = t;
  atomicAdd(cnt + t, 1);
}

__global__ __launch_bounds__(256) void k_scan1(const int* __restrict__ cnt,
                                               int* __restrict__ off,
                                               int* __restrict__ bsum) {
  __shared__ int s[256];
  int i = blockIdx.x * 256 + threadIdx.x;
  int v = (i < N) ? cnt[i] : 0;
  s[threadIdx.x] = v;
  __syncthreads();
#pragma unroll
  for (int o = 1; o < 256; o <<= 1) {
    int t = (threadIdx.x >= o) ? s[threadIdx.x - o] : 0;
    __syncthreads();
    s[threadIdx.x] += t;
    __syncthreads();
  }
  if (i < N) off[i] = s[threadIdx.x] - v;
  if (threadIdx.x == 255) bsum[blockIdx.x] = s[255];
}

__global__ __launch_bounds__(256) void k_scan2(int* __restrict__ bsum) {
  __shared__ int s[256];
  int v = (threadIdx.x < NB_SCAN) ? bsum[threadIdx.x] : 0;
  s[threadIdx.x] = v;
  __syncthreads();
#pragma unroll
  for (int o = 1; o < 256; o <<= 1) {
    int t = (threadIdx.x >= o) ? s[threadIdx.x - o] : 0;
    __syncthreads();
    s[threadIdx.x] += t;
    __syncthreads();
  }
  if (threadIdx.x < NB_SCAN) bsum[threadIdx.x] = s[threadIdx.x] - v;
}

__global__ __launch_bounds__(256) void k_scan3(int* __restrict__ off,
                                               const int* __restrict__ bsum,
                                               int* __restrict__ pos) {
  int i = blockIdx.x * 256 + threadIdx.x;
  if (i < N) {
    int o = off[i] + bsum[i >> 8];
    off[i] = o;
    pos[i] = o;
  }
  if (i == 0) off[N] = E;
}

// dst-range partitioned bucket scatter: partition = blockIdx&7 -> one XCD,
// each partition's ssrc window (~400KB) stays in that XCD's L2.
__global__ __launch_bounds__(256) void k_bucket_part(const int* __restrict__ src32,
                                                     const int* __restrict__ dst32,
                                                     int* __restrict__ pos,
                                                     int* __restrict__ ssrc) {
  const int part = blockIdx.x & (PART - 1);
  const int bi = blockIdx.x >> 3;
  const int lo = part * NPN;
  for (int e = bi * 256 + threadIdx.x; e < E; e += BLK_PER_PART * 256) {
    int d = dst32[e];
    if ((unsigned)(d - lo) < (unsigned)NPN) {
      int p = atomicAdd(pos + d, 1);
      ssrc[p] = src32[e];
    }
  }
}

// ---------------- conversions ----------------
__global__ __launch_bounds__(256) void k_cvt(const float* __restrict__ in,
                                             f16* __restrict__ out) {
  int i = blockIdx.x * 256 + threadIdx.x;
  float4 v0 = *(const float4*)(in + (size_t)i * 8);
  float4 v1 = *(const float4*)(in + (size_t)i * 8 + 4);
  f16x8 o = {(f16)v0.x, (f16)v0.y, (f16)v0.z, (f16)v0.w,
             (f16)v1.x, (f16)v1.y, (f16)v1.z, (f16)v1.w};
  *(f16x8*)(out + (size_t)i * 8) = o;
}

// weights: Wt[m][c][k] = Wsrc[m][k][c] as f16, m in [0,2L): first L from W1, rest W2
__global__ __launch_bounds__(256) void k_wprep(const float* __restrict__ W1,
                                               const float* __restrict__ W2,
                                               f16* __restrict__ Wt) {
  int i = blockIdx.x * 256 + threadIdx.x;  // 2*L*D*D = 98304, grid exact
  int m = i >> 14;
  int c = (i >> 7) & 127;
  int k = i & 127;
  const float* src = (m < L) ? (W1 + (size_t)m * D * D)
                             : (W2 + (size_t)(m - L) * D * D);
  Wt[i] = (f16)src[(size_t)k * D + c];
}

// ---------------- gather-aggregate (f16): agg[n] = x[n] + sum_{j} x[src_j]
// 16 nodes/block x 16 lanes; lane owns 8 dims (16B). 4-way unrolled neighbor
// loop keeps 4 independent row loads in flight (latency-bound access).
__global__ __launch_bounds__(256) void k_gather_f16(const f16* __restrict__ x,
                                                    const int* __restrict__ off,
                                                    const int* __restrict__ ssrc,
                                                    f16* __restrict__ agg) {
  int n = blockIdx.x * 16 + (threadIdx.x >> 4);
  if (n >= N) return;
  const int d0 = (threadIdx.x & 15) << 3;
  f16x8 v = *(const f16x8*)(x + (size_t)n * D + d0);
  float acc[8];
#pragma unroll
  for (int j = 0; j < 8; ++j) acc[j] = (float)v[j];
  const int beg = off[n], end = off[n + 1];
  int p = beg;
  for (; p + 4 <= end; p += 4) {
    int s0 = ssrc[p];
    int s1 = ssrc[p + 1];
    int s2 = ssrc[p + 2];
    int s3 = ssrc[p + 3];
    f16x8 u0 = *(const f16x8*)(x + (size_t)s0 * D + d0);
    f16x8 u1 = *(const f16x8*)(x + (size_t)s1 * D + d0);
    f16x8 u2 = *(const f16x8*)(x + (size_t)s2 * D + d0);
    f16x8 u3 = *(const f16x8*)(x + (size_t)s3 * D + d0);
#pragma unroll
    for (int j = 0; j < 8; ++j)
      acc[j] += (float)u0[j] + (float)u1[j] + (float)u2[j] + (float)u3[j];
  }
  for (; p < end; ++p) {
    int s = ssrc[p];
    f16x8 u = *(const f16x8*)(x + (size_t)s * D + d0);
#pragma unroll
    for (int j = 0; j < 8; ++j) acc[j] += (float)u[j];
  }
  f16x8 o;
#pragma unroll
  for (int j = 0; j < 8; ++j) o[j] = (f16)acc[j];
  *(f16x8*)(agg + (size_t)n * D + d0) = o;
}

// ---------------- fused double MFMA GEMM + bias + ReLU ----------------
// x' = relu(relu(A@W1+b1)@W2+b2). A f16 row-major; Wt* f16 [col][k].
// Block: 256 thr = 4 waves, 64 rows. h (64x128 f16) never leaves LDS:
// phase A -> barrier -> h into retired W1 buffer -> barrier -> phase B.
__global__ __launch_bounds__(256) void k_gemm_fused(const f16* __restrict__ A,
                                                    const f16* __restrict__ Wt1,
                                                    const f16* __restrict__ Wt2,
                                                    const float* __restrict__ b1,
                                                    const float* __restrict__ b2,
                                                    f16* __restrict__ Ch,
                                                    float* __restrict__ Cf) {
  __shared__ f16 Ws[2][128 * WROW];
  {
    const f16x8* g1 = (const f16x8*)Wt1;
    const f16x8* g2 = (const f16x8*)Wt2;
    for (int i = threadIdx.x; i < 2048; i += 256) {
      int c = i >> 4;
      int k8 = (i & 15) << 3;
      *(f16x8*)&Ws[0][c * WROW + k8] = g1[i];
      *(f16x8*)&Ws[1][c * WROW + k8] = g2[i];
    }
  }
  __syncthreads();

  const int w = threadIdx.x >> 6;   // wave 0..3
  const int l = threadIdx.x & 63;
  const int l15 = l & 15;
  const int g = l >> 4;             // 0..3
  const int r0 = blockIdx.x * 64 + w * 16;

  // ---- phase A: h = relu(A @ W1 + b1) ----
  const int arow = min(r0 + l15, N - 1);
  const f16* Arow = A + (size_t)arow * D;
  f16x8 a[4];
#pragma unroll
  for (int t = 0; t < 4; ++t)
    a[t] = *(const f16x8*)(Arow + t * 32 + g * 8);

  float bc1[8], bc2[8];
#pragma unroll
  for (int c = 0; c < 8; ++c) {
    bc1[c] = b1[c * 16 + l15];
    bc2[c] = b2[c * 16 + l15];
  }

  f32x4 acc[8];
#pragma unroll
  for (int c = 0; c < 8; ++c) acc[c] = (f32x4){0.f, 0.f, 0.f, 0.f};
#pragma unroll
  for (int t = 0; t < 4; ++t) {
#pragma unroll
    for (int c = 0; c < 8; ++c) {
      f16x8 b = *(const f16x8*)&Ws[0][(c * 16 + l15) * WROW + t * 32 + g * 8];
      acc[c] = __builtin_amdgcn_mfma_f32_16x16x32_f16(a[t], b, acc[c], 0, 0, 0);
    }
  }

  __syncthreads();  // all waves done reading Ws[0]

  // h tile (64 rows x 128 cols) into the retired W1 buffer, row-major padded.
  f16* hbuf = &Ws[0][0];
#pragma unroll
  for (int r = 0; r < 4; ++r) {
    int hr = w * 16 + g * 4 + r;  // row within block tile
#pragma unroll
    for (int c = 0; c < 8; ++c) {
      float vv = fmaxf(acc[c][r] + bc1[c], 0.0f);
      hbuf[hr * WROW + c * 16 + l15] = (f16)vv;
    }
  }
  __syncthreads();

  // ---- phase B: x' = relu(h @ W2 + b2) ----
  f16x8 a2[4];
#pragma unroll
  for (int t = 0; t < 4; ++t)
    a2[t] = *(const f16x8*)&hbuf[(w * 16 + l15) * WROW + t * 32 + g * 8];

#pragma unroll
  for (int c = 0; c < 8; ++c) acc[c] = (f32x4){0.f, 0.f, 0.f, 0.f};
#pragma unroll
  for (int t = 0; t < 4; ++t) {
#pragma unroll
    for (int c = 0; c < 8; ++c) {
      f16x8 b = *(const f16x8*)&Ws[1][(c * 16 + l15) * WROW + t * 32 + g * 8];
      acc[c] = __builtin_amdgcn_mfma_f32_16x16x32_f16(a2[t], b, acc[c], 0, 0, 0);
    }
  }

#pragma unroll
  for (int r = 0; r < 4; ++r) {
    int rr = r0 + g * 4 + r;
    if (rr < N) {
#pragma unroll
      for (int c = 0; c < 8; ++c) {
        int col = c * 16 + l15;
        float vv = fmaxf(acc[c][r] + bc2[c], 0.0f);
        Ch[(size_t)rr * D + col] = (f16)vv;
        if (Cf) Cf[(size_t)rr * D + col] = vv;
      }
    }
  }
}

extern "C" void kernel_launch(void* const* d_in, const int* in_sizes, int n_in,
                              void* d_out, int out_size, void* d_ws, size_t ws_size,
                              hipStream_t stream) {
  const float* x0 = (const float*)d_in[0];
  const int* ei   = (const int*)d_in[1];
  const float* W1 = (const float*)d_in[2];
  const float* b1 = (const float*)d_in[3];
  const float* W2 = (const float*)d_in[4];
  const float* b2 = (const float*)d_in[5];
  float* out = (float*)d_out;

  // workspace layout
  f16* xh    = (f16*)d_ws;                          // N*D
  f16* aggh  = xh + (size_t)N * D;                  // N*D
  f16* Wt    = aggh + (size_t)N * D;                // 2*L*D*D
  int* off   = (int*)(Wt + (size_t)2 * L * D * D);  // N+1
  int* pos   = off + (N + 1);                       // N
  int* bsum  = pos + N;                             // 256
  int* ssrc  = bsum + 256;                          // E
  int* src32 = ssrc + E;                            // E
  int* dst32 = src32 + E;                           // E

  const dim3 blk(256);

  // ---- one-time prep ----
  k_wprep<<<(2 * L * D * D) / 256, blk, 0, stream>>>(W1, W2, Wt);
  k_cvt<<<(N * D / 8 + 255) / 256, blk, 0, stream>>>(x0, xh);

  hipMemsetAsync(pos, 0, (size_t)N * sizeof(int), stream);
  k_prep<<<(E + 255) / 256, blk, 0, stream>>>(ei, src32, dst32, pos);
  k_scan1<<<NB_SCAN, blk, 0, stream>>>(pos, off, bsum);
  k_scan2<<<1, blk, 0, stream>>>(bsum);
  k_scan3<<<NB_SCAN, blk, 0, stream>>>(off, bsum, pos);
  k_bucket_part<<<PART * BLK_PER_PART, blk, 0, stream>>>(src32, dst32, pos, ssrc);

  const int gemm_blocks = (N + 63) / 64;  // 782
  const int gather_blocks = N / 16;       // 3125

  for (int l = 0; l < L; ++l) {
    k_gather_f16<<<gather_blocks, blk, 0, stream>>>(xh, off, ssrc, aggh);
    k_gemm_fused<<<gemm_blocks, blk, 0, stream>>>(
        aggh, Wt + (size_t)l * D * D, Wt + (size_t)(L + l) * D * D,
        b1 + (size_t)l * D, b2 + (size_t)l * D, xh,
        (l == L - 1) ? out : nullptr);
  }
}